// Round 1
// baseline (147.648 us; speedup 1.0000x reference)
//
#include <hip/hip_runtime.h>

// VectorQuantizer: N=131072 tokens, D=64, K=1024 codes.
// out (f32 concat): [0,8388608) quant, [8388608] loss, [8388609,...) idx.
//
// R11: LDS-resident B restructure + launch fusion.
// R10 counters: dist=69us with MfmaUtil 30 / VALUBusy 34 / HBM 9.5% -> ~45us
// of stall from 16 barrier-separated global->LDS staging stages; plus ~60us
// of launch overhead across 3 launches.
//  - B-fragments now LIVE in LDS: 4 passes x 256 codes (64KB), rebuilt 3x
//    per block straight from emb (L2-hot, coalesced 32B/thread tasks).
//    vq_setup is gone entirely -> 2 launches.
//  - Each wave owns 32 tokens for the WHOLE kernel: A-frags + x2 built once,
//    reused across all 4 passes. Inner loop = 16 code-tiles x 12 MFMA with
//    ZERO barriers (was: barrier every 4 tiles). ~8 barriers/block vs 16.
//  - 2 blocks/CU (69KB LDS, launch_bounds(512,4)): sibling block's MFMA
//    hides this block's rebuild + barrier drain.
// Distance math bit-identical to R4-R10: fp16 split-product MFMA
// (hi*hi+hi*lo+lo*hi), np8 x2/e2, s=fma(-2,dot,x2+e2), ascending-k strict-<
// first-min, butterfly epilogue, bitwise quant copy.

#define KC 1024
#define DD 64
#define NTOK (32 * 4096)
#define QUANT_ELEMS ((size_t)NTOK * DD)        // 8388608
#define LOSS_OFF QUANT_ELEMS
#define IDX_OFF (QUANT_ELEMS + 1)

#define MAIN_BLOCKS (NTOK / 256)   // 512 blocks, 256 tokens each
#define NPASS 4
#define CODES_PP (KC / NPASS)      // 256 codes per pass
#define TILES_PP (CODES_PP / 16)   // 16 tiles of 16 codes

typedef _Float16 f16x8 __attribute__((ext_vector_type(8)));
typedef float f32x4 __attribute__((ext_vector_type(4)));

__device__ __forceinline__ unsigned int sortable_bits(float f) {
  unsigned int b = __float_as_uint(f);
  return b ^ (unsigned int)(((int)b >> 31) | 0x80000000);
}

__device__ __forceinline__ float unsortable_bits(unsigned int u) {
  unsigned int fb = (u & 0x80000000u) ? (u ^ 0x80000000u) : ~u;
  return __uint_as_float(fb);
}

// np pairwise-8 sum of squares of a 64-float row (bit-identical to R10)
__device__ __forceinline__ float row_sumsq_np8(const float* p) {
  float r[8];
#pragma unroll
  for (int j = 0; j < 8; ++j) r[j] = p[j] * p[j];
#pragma unroll
  for (int i = 1; i < 8; ++i)
#pragma unroll
    for (int j = 0; j < 8; ++j) {
      float v = p[i * 8 + j];
      r[j] += v * v;
    }
  return ((r[0] + r[1]) + (r[2] + r[3])) + ((r[4] + r[5]) + (r[6] + r[7]));
}

__launch_bounds__(512, 4)
__global__ void vq_main(const float* __restrict__ x_in,
                        const float* __restrict__ emb,
                        float* __restrict__ out,
                        float* __restrict__ blocksum) {
  const int tid = threadIdx.x;
  const int wave = tid >> 6, lane = tid & 63;
  const int quad = lane >> 4, l16 = lane & 15;
  const int tokBase = blockIdx.x * 256 + wave * 32;  // 32 tokens per wave

  __shared__ f16x8 Bl[TILES_PP * 4 * 64];  // 64 KB: one pass of B-frags
  __shared__ float E2s[KC];                // 4 KB
  __shared__ float x2s[256];               // per-block token x2
  __shared__ float wsum[8];

  // Build pass-p B-fragments from emb. 2048 tasks of 32B (one row x 8-dim
  // chunk each, producing hi+lo f16x8); thread tid takes tasks t*512+tid ->
  // fully coalesced 32B/lane global reads. Frag layout identical to R10's
  // vq_setup: tile nt, f = plane*2 + ks, lane = (row&15) | (chunk&3)<<4.
  auto build_B = [&](int p) {
#pragma unroll
    for (int t = 0; t < 4; ++t) {
      const int idx = t * 512 + tid;       // 0..2047
      const int nl = idx >> 3;             // local code row 0..255
      const int c = idx & 7;               // 8-dim chunk 0..7
      const int ks = c >> 2;
      const int ln = (nl & 15) | ((c & 3) << 4);
      const int nt = nl >> 4;
      const float4* src =
          (const float4*)(emb + (size_t)(p * CODES_PP + nl) * DD + c * 8);
      float4 v0 = src[0], v1 = src[1];
      float vv[8] = {v0.x, v0.y, v0.z, v0.w, v1.x, v1.y, v1.z, v1.w};
      f16x8 oh, ol;
#pragma unroll
      for (int j = 0; j < 8; ++j) {
        _Float16 h = (_Float16)vv[j];
        oh[j] = h;
        ol[j] = (_Float16)(vv[j] - (float)h);
      }
      Bl[(nt * 4 + ks) * 64 + ln] = oh;      // hi plane, f = ks
      Bl[(nt * 4 + 2 + ks) * 64 + ln] = ol;  // lo plane, f = 2+ks
    }
  };

  // ---- prologue: pass-0 B, e2 table, x2, A-frags ----
  build_B(0);
  E2s[tid] = row_sumsq_np8(emb + (size_t)tid * DD);
  E2s[512 + tid] = row_sumsq_np8(emb + (size_t)(512 + tid) * DD);
  if (lane < 32)
    x2s[wave * 32 + lane] =
        row_sumsq_np8(x_in + (size_t)(tokBase + lane) * DD);

  // A fragments: 2 m-sets of 16 tokens; x split into fp16 hi/lo planes.
  // Built ONCE: the wave keeps the same 32 tokens across all 4 passes.
  f16x8 ah[2][2], al[2][2];
#pragma unroll
  for (int ms = 0; ms < 2; ++ms) {
    const float* xr = x_in + (size_t)(tokBase + ms * 16 + l16) * DD;
#pragma unroll
    for (int ks = 0; ks < 2; ++ks) {
      const float4* p4 = (const float4*)(xr + ks * 32 + quad * 8);
      float4 v0 = p4[0], v1 = p4[1];
      float vv[8] = {v0.x, v0.y, v0.z, v0.w, v1.x, v1.y, v1.z, v1.w};
#pragma unroll
      for (int j = 0; j < 8; ++j) {
        _Float16 h = (_Float16)vv[j];
        ah[ms][ks][j] = h;
        al[ms][ks][j] = (_Float16)(vv[j] - (float)h);
      }
    }
  }

  float best[2][4];
  int bidx[2][4];
#pragma unroll
  for (int ms = 0; ms < 2; ++ms)
#pragma unroll
    for (int r = 0; r < 4; ++r) { best[ms][r] = 3.402823466e38f; bidx[ms][r] = 0; }

  __syncthreads();  // Bl(pass0) + E2s + x2s ready

  // x2 for this lane's C rows: token = tokBase + ms*16 + quad*4 + r
  float x2v[2][4];
#pragma unroll
  for (int ms = 0; ms < 2; ++ms)
#pragma unroll
    for (int r = 0; r < 4; ++r)
      x2v[ms][r] = x2s[wave * 32 + ms * 16 + quad * 4 + r];

  for (int p = 0; p < NPASS; ++p) {
    // Barrier-free inner loop over this pass's 16 code-tiles.
#pragma unroll 4
    for (int lt = 0; lt < TILES_PP; ++lt) {
      const int ch = lt * 4;
      f16x8 bh0 = Bl[(ch + 0) * 64 + lane];
      f16x8 bh1 = Bl[(ch + 1) * 64 + lane];
      f16x8 bl0 = Bl[(ch + 2) * 64 + lane];
      f16x8 bl1 = Bl[(ch + 3) * 64 + lane];
      const int ncur = p * CODES_PP + lt * 16 + l16;  // this lane's code col
      const float e2v = E2s[ncur];
      f32x4 acc[2];
#pragma unroll
      for (int ms = 0; ms < 2; ++ms) acc[ms] = (f32x4){0.f, 0.f, 0.f, 0.f};
      // step-major: 2 independent chains; per-acc order identical to R4-R10
#pragma unroll
      for (int ms = 0; ms < 2; ++ms)
        acc[ms] = __builtin_amdgcn_mfma_f32_16x16x32_f16(ah[ms][0], bh0, acc[ms], 0, 0, 0);
#pragma unroll
      for (int ms = 0; ms < 2; ++ms)
        acc[ms] = __builtin_amdgcn_mfma_f32_16x16x32_f16(ah[ms][1], bh1, acc[ms], 0, 0, 0);
#pragma unroll
      for (int ms = 0; ms < 2; ++ms)
        acc[ms] = __builtin_amdgcn_mfma_f32_16x16x32_f16(al[ms][0], bh0, acc[ms], 0, 0, 0);
#pragma unroll
      for (int ms = 0; ms < 2; ++ms)
        acc[ms] = __builtin_amdgcn_mfma_f32_16x16x32_f16(al[ms][1], bh1, acc[ms], 0, 0, 0);
#pragma unroll
      for (int ms = 0; ms < 2; ++ms)
        acc[ms] = __builtin_amdgcn_mfma_f32_16x16x32_f16(ah[ms][0], bl0, acc[ms], 0, 0, 0);
#pragma unroll
      for (int ms = 0; ms < 2; ++ms)
        acc[ms] = __builtin_amdgcn_mfma_f32_16x16x32_f16(ah[ms][1], bl1, acc[ms], 0, 0, 0);
#pragma unroll
      for (int ms = 0; ms < 2; ++ms)
#pragma unroll
        for (int r = 0; r < 4; ++r) {
          float s = __builtin_fmaf(-2.0f, acc[ms][r], x2v[ms][r] + e2v);
          if (s < best[ms][r]) { best[ms][r] = s; bidx[ms][r] = ncur; }
        }
    }
    if (p < NPASS - 1) {
      __syncthreads();      // all waves done reading Bl
      build_B(p + 1);       // rebuild in place (L2-hot emb reads)
      __syncthreads();      // Bl(pass p+1) ready
    }
  }

  // Butterfly min across each quad's 16 lanes -> ALL lanes hold the winner.
  unsigned long long key[2][4];
#pragma unroll
  for (int ms = 0; ms < 2; ++ms)
#pragma unroll
    for (int r = 0; r < 4; ++r) {
      unsigned long long k =
          ((unsigned long long)sortable_bits(best[ms][r]) << 32) |
          (unsigned int)bidx[ms][r];
#pragma unroll
      for (int m = 1; m < 16; m <<= 1) {
        unsigned long long o = __shfl_xor(k, m);
        k = o < k ? o : k;
      }
      key[ms][r] = k;
    }

  // Fused epilogue: idx store (quad lane 0), quant gather+store (all lanes),
  // loss partial decoded from keys.
  float qsum = 0.0f;
#pragma unroll
  for (int ms = 0; ms < 2; ++ms)
#pragma unroll
    for (int r = 0; r < 4; ++r) {
      const int token = tokBase + ms * 16 + quad * 4 + r;
      const int widx = (int)(unsigned int)key[ms][r];
      if (l16 == 0) out[IDX_OFF + (size_t)token] = (float)widx;
      // 16 lanes x float4 = the winning 256B row, bitwise copy
      const float4 v = ((const float4*)(emb + (size_t)widx * DD))[l16];
      ((float4*)(out + (size_t)token * DD))[l16] = v;
      qsum += unsortable_bits((unsigned int)(key[ms][r] >> 32));
    }

  // qsum identical across a quad's 16 lanes; sum the 4 quads, then 8 waves.
  float tot = __shfl(qsum, 0) + __shfl(qsum, 16) +
              __shfl(qsum, 32) + __shfl(qsum, 48);
  if (lane == 0) wsum[wave] = tot;
  __syncthreads();
  if (tid == 0)
    blocksum[blockIdx.x] = ((wsum[0] + wsum[1]) + (wsum[2] + wsum[3])) +
                           ((wsum[4] + wsum[5]) + (wsum[6] + wsum[7]));
}

// 1 block: reduce 512 per-block partials -> loss
__global__ void vq_finish(const float* __restrict__ blocksum,
                          float* __restrict__ out) {
  const int tid = threadIdx.x;
  float s = blocksum[tid] + blocksum[256 + tid];
#pragma unroll
  for (int off = 32; off > 0; off >>= 1) s += __shfl_down(s, off);
  __shared__ float wsum[4];
  const int wid = tid >> 6;
  if ((tid & 63) == 0) wsum[wid] = s;
  __syncthreads();
  if (tid == 0) {
    float total = (wsum[0] + wsum[1]) + (wsum[2] + wsum[3]);
    float m = total / (float)QUANT_ELEMS;
    out[LOSS_OFF] = m + 0.25f * m;  // q_latent + COMMITMENT_COST * e_latent
  }
}

extern "C" void kernel_launch(void* const* d_in, const int* in_sizes, int n_in,
                              void* d_out, int out_size, void* d_ws, size_t ws_size,
                              hipStream_t stream) {
  const float* x = (const float*)d_in[0];
  const float* emb = (const float*)d_in[1];
  float* out = (float*)d_out;
  float* ws = (float*)d_ws;

  vq_main<<<MAIN_BLOCKS, 512, 0, stream>>>(x, emb, out, ws);
  vq_finish<<<1, 256, 0, stream>>>(ws, out);
}

// Round 2
// 138.731 us; speedup vs baseline: 1.0643x; 1.0643x over previous
//
#include <hip/hip_runtime.h>

// VectorQuantizer: N=131072 tokens, D=64, K=1024 codes.
// out (f32 concat): [0,8388608) quant, [8388608] loss, [8388609,...) idx.
//
// R12: barrier-free register-streamed B.
// R11 post-mortem: LDS-resident B regressed (86.8us) -- build_B writes were
// 8-way bank-conflicted (7.3M conflicts) and the in-place rebuild forced two
// full barrier drains per pass with no overlap. Reverted.
// R10 post-mortem: 69us at MfmaUtil 30% = the classic 2-barrier-per-stage
// staging ceiling; ~45us of barrier/staging stall over a ~21-25us MFMA floor.
// R12 structure:
//  - B-fragments streamed global->REGISTER per wave from ws (256KB, L2/L3
//    resident; prebuilt by the proven R10 setup kernel). No LDS for B, no
//    double-buffer barriers: ONE __syncthreads in the whole kernel.
//  - 64 tokens/wave (4 m-sets) halves per-token fragment traffic (L2 floor
//    ~21us < MFMA floor ~25us) and gives 24 MFMA per 4 global loads.
//  - 1-deep register prefetch (load tile nt+1 while computing nt); compiler
//    emits counted vmcnt, nothing ever drains to 0 mid-loop.
//  - s_setprio(1) around the MFMA cluster (independent free-running waves --
//    the regime where setprio measured +4-7%).
// Distance math bit-identical to R4-R10: fp16 split-product MFMA
// (hi*hi+hi*lo+lo*hi) in the same per-accumulator order, np8 x2/e2,
// s=fma(-2,dot,x2+e2), ascending-k strict-< first-min, butterfly epilogue,
// bitwise quant copy.

#define KC 1024
#define DD 64
#define NTOK (32 * 4096)
#define QUANT_ELEMS ((size_t)NTOK * DD)        // 8388608
#define LOSS_OFF QUANT_ELEMS
#define IDX_OFF (QUANT_ELEMS + 1)

// ws float-word offsets (layout identical to R10)
#define WS_E2 0                      // 1024 f32
#define WS_BFRAG_F 2048              // 16384 f16x8 = 65536 f32 words
#define WS_BSUM (WS_BFRAG_F + 65536) // per-block loss partials

#define MAIN_BLOCKS (NTOK / 256)     // 512 blocks, 256 tokens each

typedef _Float16 f16x8 __attribute__((ext_vector_type(8)));
typedef float f32x4 __attribute__((ext_vector_type(4)));

__device__ __forceinline__ unsigned int sortable_bits(float f) {
  unsigned int b = __float_as_uint(f);
  return b ^ (unsigned int)(((int)b >> 31) | 0x80000000);
}

__device__ __forceinline__ float unsortable_bits(unsigned int u) {
  unsigned int fb = (u & 0x80000000u) ? (u ^ 0x80000000u) : ~u;
  return __uint_as_float(fb);
}

// np pairwise-8 sum of squares of a 64-float row (bit-identical to R10)
__device__ __forceinline__ float row_sumsq_np8(const float* p) {
  float r[8];
#pragma unroll
  for (int j = 0; j < 8; ++j) r[j] = p[j] * p[j];
#pragma unroll
  for (int i = 1; i < 8; ++i)
#pragma unroll
    for (int j = 0; j < 8; ++j) {
      float v = p[i * 8 + j];
      r[j] += v * v;
    }
  return ((r[0] + r[1]) + (r[2] + r[3])) + ((r[4] + r[5]) + (r[6] + r[7]));
}

// blocks [0,64): B-frag build; [64,68): e2 table  (verbatim R10)
__global__ void vq_setup(const float* __restrict__ emb,
                         float* __restrict__ ws) {
  const int b = blockIdx.x;
  const int tid = threadIdx.x;
  if (b < 64) {
    const int nt = b;                  // global tile 0..63 (16 codes each)
    const int f = tid >> 6;            // 0..3: plane(hi/lo) x kstep
    const int lane = tid & 63;
    const int plane = f >> 1, ks = f & 1;
    const int n = nt * 16 + (lane & 15);
    const int kb = ks * 32 + ((lane >> 4) & 3) * 8;
    const float* ep = emb + (size_t)n * DD + kb;
    f16x8 o;
#pragma unroll
    for (int j = 0; j < 8; ++j) {
      float v = ep[j];
      _Float16 h = (_Float16)v;
      o[j] = (plane == 0) ? h : (_Float16)(v - (float)h);
    }
    ((f16x8*)(ws + WS_BFRAG_F))[(nt * 4 + f) * 64 + lane] = o;
  } else {
    const int k = (b - 64) * 256 + tid;  // 0..1023
    ws[WS_E2 + k] = row_sumsq_np8(emb + (size_t)k * DD);
  }
}

__launch_bounds__(256, 2)
__global__ void vq_main(const float* __restrict__ x_in,
                        const float* __restrict__ emb,
                        const float* __restrict__ ws_ro,
                        float* __restrict__ out,
                        float* __restrict__ blocksum) {
  const int tid = threadIdx.x;
  const int wave = tid >> 6, lane = tid & 63;
  const int quad = lane >> 4, l16 = lane & 15;
  const int tokBase = blockIdx.x * 256 + wave * 64;  // 64 tokens per wave

  __shared__ float E2s[KC];    // 4 KB
  __shared__ float x2s[256];   // per-block token x2
  __shared__ float wsum[4];

  // Stage e2 table to LDS; x2 for this wave's 64 tokens (one row per lane,
  // bit-identical np8 -- value depends only on row data, not producer lane).
#pragma unroll
  for (int i = 0; i < 4; ++i)
    E2s[i * 256 + tid] = ws_ro[WS_E2 + i * 256 + tid];
  x2s[wave * 64 + lane] = row_sumsq_np8(x_in + (size_t)(tokBase + lane) * DD);

  // A fragments: 4 m-sets of 16 tokens; x split into fp16 hi/lo planes.
  f16x8 ah[4][2], al[4][2];
#pragma unroll
  for (int ms = 0; ms < 4; ++ms) {
    const float* xr = x_in + (size_t)(tokBase + ms * 16 + l16) * DD;
#pragma unroll
    for (int ks = 0; ks < 2; ++ks) {
      const float4* p4 = (const float4*)(xr + ks * 32 + quad * 8);
      float4 v0 = p4[0], v1 = p4[1];
      float vv[8] = {v0.x, v0.y, v0.z, v0.w, v1.x, v1.y, v1.z, v1.w};
#pragma unroll
      for (int j = 0; j < 8; ++j) {
        _Float16 h = (_Float16)vv[j];
        ah[ms][ks][j] = h;
        al[ms][ks][j] = (_Float16)(vv[j] - (float)h);
      }
    }
  }

  float best[4][4];
  int bidx[4][4];
#pragma unroll
  for (int ms = 0; ms < 4; ++ms)
#pragma unroll
    for (int r = 0; r < 4; ++r) { best[ms][r] = 3.402823466e38f; bidx[ms][r] = 0; }

  __syncthreads();  // E2s + x2s ready -- the ONLY barrier before epilogue

  // x2 for this lane's C rows: token = tokBase + ms*16 + quad*4 + r
  float x2v[4][4];
#pragma unroll
  for (int ms = 0; ms < 4; ++ms)
#pragma unroll
    for (int r = 0; r < 4; ++r)
      x2v[ms][r] = x2s[wave * 64 + ms * 16 + quad * 4 + r];

  const f16x8* bws = (const f16x8*)(ws_ro + WS_BFRAG_F);

  // Per-tile compute: 24 MFMA (6-product chain per ms, order identical to
  // R4-R10, step-major across the 4 independent chains) + first-min update.
  auto compute = [&](int nt, const f16x8 (&bf)[4]) {
    const int ncur = nt * 16 + l16;       // this lane's code column
    const float e2v = E2s[ncur];
    f32x4 acc[4];
#pragma unroll
    for (int ms = 0; ms < 4; ++ms) acc[ms] = (f32x4){0.f, 0.f, 0.f, 0.f};
    __builtin_amdgcn_s_setprio(1);
#pragma unroll
    for (int ms = 0; ms < 4; ++ms)
      acc[ms] = __builtin_amdgcn_mfma_f32_16x16x32_f16(ah[ms][0], bf[0], acc[ms], 0, 0, 0);
#pragma unroll
    for (int ms = 0; ms < 4; ++ms)
      acc[ms] = __builtin_amdgcn_mfma_f32_16x16x32_f16(ah[ms][1], bf[1], acc[ms], 0, 0, 0);
#pragma unroll
    for (int ms = 0; ms < 4; ++ms)
      acc[ms] = __builtin_amdgcn_mfma_f32_16x16x32_f16(al[ms][0], bf[0], acc[ms], 0, 0, 0);
#pragma unroll
    for (int ms = 0; ms < 4; ++ms)
      acc[ms] = __builtin_amdgcn_mfma_f32_16x16x32_f16(al[ms][1], bf[1], acc[ms], 0, 0, 0);
#pragma unroll
    for (int ms = 0; ms < 4; ++ms)
      acc[ms] = __builtin_amdgcn_mfma_f32_16x16x32_f16(ah[ms][0], bf[2], acc[ms], 0, 0, 0);
#pragma unroll
    for (int ms = 0; ms < 4; ++ms)
      acc[ms] = __builtin_amdgcn_mfma_f32_16x16x32_f16(ah[ms][1], bf[3], acc[ms], 0, 0, 0);
    __builtin_amdgcn_s_setprio(0);
#pragma unroll
    for (int ms = 0; ms < 4; ++ms)
#pragma unroll
      for (int r = 0; r < 4; ++r) {
        float s = __builtin_fmaf(-2.0f, acc[ms][r], x2v[ms][r] + e2v);
        if (s < best[ms][r]) { best[ms][r] = s; bidx[ms][r] = ncur; }
      }
  };

  // Barrier-free main loop: 64 code-tiles, 1-deep register prefetch.
  f16x8 bA[4], bB[4];
#pragma unroll
  for (int i = 0; i < 4; ++i) bA[i] = bws[i * 64 + lane];

  for (int nt = 0; nt < 64; nt += 2) {
#pragma unroll
    for (int i = 0; i < 4; ++i) bB[i] = bws[((nt + 1) * 4 + i) * 64 + lane];
    compute(nt, bA);
    if (nt + 2 < 64) {
#pragma unroll
      for (int i = 0; i < 4; ++i) bA[i] = bws[((nt + 2) * 4 + i) * 64 + lane];
    }
    compute(nt + 1, bB);
  }

  // Butterfly min across each quad's 16 lanes -> ALL lanes hold the winner.
  unsigned long long key[4][4];
#pragma unroll
  for (int ms = 0; ms < 4; ++ms)
#pragma unroll
    for (int r = 0; r < 4; ++r) {
      unsigned long long k =
          ((unsigned long long)sortable_bits(best[ms][r]) << 32) |
          (unsigned int)bidx[ms][r];
#pragma unroll
      for (int m = 1; m < 16; m <<= 1) {
        unsigned long long o = __shfl_xor(k, m);
        k = o < k ? o : k;
      }
      key[ms][r] = k;
    }

  // Fused epilogue: idx store (quad lane 0), quant gather+store (all lanes),
  // loss partial decoded from keys.
  float qsum = 0.0f;
#pragma unroll
  for (int ms = 0; ms < 4; ++ms)
#pragma unroll
    for (int r = 0; r < 4; ++r) {
      const int token = tokBase + ms * 16 + quad * 4 + r;
      const int widx = (int)(unsigned int)key[ms][r];
      if (l16 == 0) out[IDX_OFF + (size_t)token] = (float)widx;
      // 16 lanes x float4 = the winning 256B row, bitwise copy
      const float4 v = ((const float4*)(emb + (size_t)widx * DD))[l16];
      ((float4*)(out + (size_t)token * DD))[l16] = v;
      qsum += unsortable_bits((unsigned int)(key[ms][r] >> 32));
    }

  // qsum identical across a quad's 16 lanes; sum the 4 quads, then 4 waves.
  float tot = __shfl(qsum, 0) + __shfl(qsum, 16) +
              __shfl(qsum, 32) + __shfl(qsum, 48);
  if (lane == 0) wsum[wave] = tot;
  __syncthreads();
  if (tid == 0)
    blocksum[blockIdx.x] = (wsum[0] + wsum[1]) + (wsum[2] + wsum[3]);
}

// 1 block: reduce 512 per-block partials -> loss
__global__ void vq_finish(const float* __restrict__ blocksum,
                          float* __restrict__ out) {
  const int tid = threadIdx.x;
  float s = blocksum[tid] + blocksum[256 + tid];
#pragma unroll
  for (int off = 32; off > 0; off >>= 1) s += __shfl_down(s, off);
  __shared__ float wsum[4];
  const int wid = tid >> 6;
  if ((tid & 63) == 0) wsum[wid] = s;
  __syncthreads();
  if (tid == 0) {
    float total = (wsum[0] + wsum[1]) + (wsum[2] + wsum[3]);
    float m = total / (float)QUANT_ELEMS;
    out[LOSS_OFF] = m + 0.25f * m;  // q_latent + COMMITMENT_COST * e_latent
  }
}

extern "C" void kernel_launch(void* const* d_in, const int* in_sizes, int n_in,
                              void* d_out, int out_size, void* d_ws, size_t ws_size,
                              hipStream_t stream) {
  const float* x = (const float*)d_in[0];
  const float* emb = (const float*)d_in[1];
  float* out = (float*)d_out;
  float* ws = (float*)d_ws;

  vq_setup<<<68, 256, 0, stream>>>(emb, ws);
  vq_main<<<MAIN_BLOCKS, 256, 0, stream>>>(x, emb, ws, out, ws + WS_BSUM);
  vq_finish<<<1, 256, 0, stream>>>(ws + WS_BSUM, out);
}